// Round 1
// baseline (158.499 us; speedup 1.0000x reference)
//
#include <hip/hip_runtime.h>
#include <cmath>

#define B_N 65536
#define C_N 128
#define D_N 32
#define K_N 10
#define EPS_F 1e-12f
#define SCALE_F (-0.72134752044448169f)   // -0.5 * log2(e)

#define NKK 45                   // MFMA K-steps (K = 45*16 = 720 slots, 561 live)
#define QFRAG_N (4 * NKK * 64 * 8)   // 92160 fp16 elements per (hi|lo) array

typedef _Float16 f16x8 __attribute__((ext_vector_type(8)));
typedef float    f32x16 __attribute__((ext_vector_type(16)));

// Window tables: K-step kk covers triangle row pair (WDT[kk], WDT[kk]+1),
// e-window [WET[kk], WET[kk]+8). lane-half (lane>>5) selects which row of the
// pair; slot invalid (Q=0) when d>e or e>32. Last step is row 32 (homog const).
static constexpr int WDT[NKK] = {
    0,0,0,0,0,  2,2,2,2,  4,4,4,4,  6,6,6,6,  8,8,8,8,
    10,10,10, 12,12,12, 14,14,14, 16,16,16,
    18,18, 20,20, 22,22, 24,24, 26, 28, 30, 32};
static constexpr int WET[NKK] = {
    0,8,16,24,32,  2,10,18,26,  4,12,20,28,  6,14,22,30,  8,16,24,32,
    10,18,26, 12,20,28, 14,22,30, 16,24,32,
    18,26, 20,28, 22,30, 24,32, 26, 28, 30, 32};

// ---------------------------------------------------------------------------
// Prep 1: Sm[c][d] = sum_e S_inv[c][d][e] * mu[c][e]
// ---------------------------------------------------------------------------
__global__ __launch_bounds__(256) void k_prep_sm(const float* __restrict__ S,
                                                 const float* __restrict__ mu,
                                                 float* __restrict__ Sm) {
    int t = blockIdx.x * 256 + threadIdx.x;     // 0..4095
    int c = t >> 5;
    int d = t & 31;
    const float* Sr = S + (size_t)c * (D_N * D_N) + (size_t)d * D_N;
    const float* mr = mu + (size_t)c * D_N;
    float a0 = 0.f, a1 = 0.f, a2 = 0.f, a3 = 0.f;
#pragma unroll
    for (int e = 0; e < D_N; e += 4) {
        a0 = fmaf(Sr[e + 0], mr[e + 0], a0);
        a1 = fmaf(Sr[e + 1], mr[e + 1], a1);
        a2 = fmaf(Sr[e + 2], mr[e + 2], a2);
        a3 = fmaf(Sr[e + 3], mr[e + 3], a3);
    }
    Sm[t] = (a0 + a1) + (a2 + a3);
}

// ---------------------------------------------------------------------------
// Prep 2: t3[c] = mu[c].Sm[c];  cls[c] = argmax_k onehot[c][k]
// ---------------------------------------------------------------------------
__global__ __launch_bounds__(128) void k_prep_misc(const float* __restrict__ mu,
                                                   const float* __restrict__ Sm,
                                                   const int* __restrict__ onehot,
                                                   float* __restrict__ t3,
                                                   int* __restrict__ cls) {
    int c = threadIdx.x;
    const float* mr = mu + (size_t)c * D_N;
    const float* sr = Sm + (size_t)c * D_N;
    float a = 0.f;
#pragma unroll
    for (int d = 0; d < D_N; ++d) a = fmaf(mr[d], sr[d], a);
    t3[c] = a;
    int cl = 0;
#pragma unroll
    for (int k = 0; k < K_N; ++k)
        if (onehot[c * K_N + k] != 0) cl = k;
    cls[c] = cl;
}

// ---------------------------------------------------------------------------
// Prep 3: pack Q fragments in MFMA A-operand order, fp16 hi/lo split.
// Element t = ((ct*NKK + kk)*64 + lane)*8 + j holds Q[c = ct*32 + (lane&31)]
// for feature (d = 2r + (lane>>5), e = e0 + j) of K-step kk.
// Q value: SCALE * ( d<e<32: 2*S[d][e] | d==e<32: S[d][d] |
//                    d<32,e==32: -2*Sm[d] | d==e==32: t3 | else 0 )
// ---------------------------------------------------------------------------
__global__ __launch_bounds__(256) void k_packfrag(const float* __restrict__ S,
                                                  const float* __restrict__ Sm,
                                                  const float* __restrict__ t3,
                                                  _Float16* __restrict__ Qh,
                                                  _Float16* __restrict__ Ql) {
    int t = blockIdx.x * 256 + threadIdx.x;
    if (t >= QFRAG_N) return;
    int j    = t & 7;
    int lane = (t >> 3) & 63;
    int rest = t >> 9;            // ct*NKK + kk
    int kk   = rest % NKK;
    int ct   = rest / NKK;
    // decode window: r such that kk falls in row-pair r's window list
    int r = 0, base = 0;
    for (;;) {
        int w = (40 - 2 * r) >> 3;          // windows for pair r (r=16 -> 1)
        if (kk < base + w) break;
        base += w; ++r;
    }
    int e0 = 2 * r + 8 * (kk - base);
    int d  = 2 * r + (lane >> 5);
    int e  = e0 + j;
    int c  = ct * 32 + (lane & 31);
    float q = 0.f;
    if (d <= e && e <= 32) {
        float v;
        if (e < 32)      v = S[(size_t)c * (D_N * D_N) + d * D_N + e] * (d == e ? 1.f : 2.f);
        else if (d < 32) v = -2.f * Sm[c * D_N + d];
        else             v = t3[c];
        q = SCALE_F * v;
    }
    _Float16 h = (_Float16)q;
    Qh[t] = h;
    Ql[t] = (_Float16)(q - (float)h);
}

// ---------------------------------------------------------------------------
// Main: register-resident fp16-pair MFMA GEMM.
// acc[c][b] = sum_t Q[c][t] * phi[b][t], Gamma = exp2(acc).
// Wave owns 64 b-rows (2 groups of 32) x all 128 c (4 A-tiles).
// A = Q fragments (global, fragment-ordered); B = phi built in registers:
// lane's col = its b-row, so phi frags need only the lane's own y[].
// 4 sections: Qh*ph + Ql*ph + Qh*pl + Ql*pl  (full fp32-faithful product).
// ---------------------------------------------------------------------------
__global__ __launch_bounds__(256, 1) void k_mainv2(const float* __restrict__ data,
                                                   const _Float16* __restrict__ Qhp,
                                                   const _Float16* __restrict__ Qlp,
                                                   float* __restrict__ gws) {
    const int lane = threadIdx.x & 63;
    const int wid  = threadIdx.x >> 6;
    const int b0   = blockIdx.x * 256 + wid * 64;   // wave's first row
    const int col  = lane & 31;
    const bool hi  = lane >= 32;

    // y for the lane's two rows (b0+col, b0+32+col); [32]=1 homog, [33]=0 pad
    float y0[34], y1[34];
    {
        const float4* p0 = (const float4*)(data + (size_t)(b0 + col) * D_N);
        const float4* p1 = (const float4*)(data + (size_t)(b0 + 32 + col) * D_N);
#pragma unroll
        for (int i = 0; i < 8; ++i) {
            float4 v = p0[i];
            y0[4 * i + 0] = v.x; y0[4 * i + 1] = v.y;
            y0[4 * i + 2] = v.z; y0[4 * i + 3] = v.w;
            float4 w = p1[i];
            y1[4 * i + 0] = w.x; y1[4 * i + 1] = w.y;
            y1[4 * i + 2] = w.z; y1[4 * i + 3] = w.w;
        }
        y0[32] = 1.f; y0[33] = 0.f;
        y1[32] = 1.f; y1[33] = 0.f;
    }

    f32x16 acc[4][2];
#pragma unroll
    for (int ct = 0; ct < 4; ++ct)
#pragma unroll
        for (int bt = 0; bt < 2; ++bt)
#pragma unroll
            for (int g = 0; g < 16; ++g) acc[ct][bt][g] = 0.f;

    const f16x8* QH = (const f16x8*)Qhp;
    const f16x8* QL = (const f16x8*)Qlp;

#pragma unroll
    for (int kk = 0; kk < NKK; ++kk) {
        // A fragments: Q hi/lo for 4 c-tiles (coalesced 16B/lane, L2-resident)
        f16x8 qh[4], ql[4];
#pragma unroll
        for (int ct = 0; ct < 4; ++ct) {
            qh[ct] = QH[(ct * NKK + kk) * 64 + lane];
            ql[ct] = QL[(ct * NKK + kk) * 64 + lane];
        }

        // B fragments: phi for both b-groups, fp16 hi/lo split
        const int dA = WDT[kk];
        const int dB = dA + 1;          // <= 33 (y[33]=0)
        const int e0 = WET[kk];
        const float yd0 = hi ? y0[dB] : y0[dA];
        const float yd1 = hi ? y1[dB] : y1[dA];
        f16x8 ph0, pl0, ph1, pl1;
#pragma unroll
        for (int j = 0; j < 8; ++j) {
            const int e = e0 + j;
            float f0, f1;
            if (e <= 32) { f0 = yd0 * y0[e]; f1 = yd1 * y1[e]; }
            else         { f0 = 0.f;         f1 = 0.f; }
            _Float16 h0 = (_Float16)f0;
            ph0[j] = h0;
            pl0[j] = (_Float16)(f0 - (float)h0);
            _Float16 h1 = (_Float16)f1;
            ph1[j] = h1;
            pl1[j] = (_Float16)(f1 - (float)h1);
        }

        // 32 MFMAs: 4 c-tiles x 2 b-groups x 4 sections (8 indep acc chains)
#pragma unroll
        for (int ct = 0; ct < 4; ++ct) {
            acc[ct][0] = __builtin_amdgcn_mfma_f32_32x32x16_f16(qh[ct], ph0, acc[ct][0], 0, 0, 0);
            acc[ct][1] = __builtin_amdgcn_mfma_f32_32x32x16_f16(qh[ct], ph1, acc[ct][1], 0, 0, 0);
            acc[ct][0] = __builtin_amdgcn_mfma_f32_32x32x16_f16(ql[ct], ph0, acc[ct][0], 0, 0, 0);
            acc[ct][1] = __builtin_amdgcn_mfma_f32_32x32x16_f16(ql[ct], ph1, acc[ct][1], 0, 0, 0);
            acc[ct][0] = __builtin_amdgcn_mfma_f32_32x32x16_f16(qh[ct], pl0, acc[ct][0], 0, 0, 0);
            acc[ct][1] = __builtin_amdgcn_mfma_f32_32x32x16_f16(qh[ct], pl1, acc[ct][1], 0, 0, 0);
            acc[ct][0] = __builtin_amdgcn_mfma_f32_32x32x16_f16(ql[ct], pl0, acc[ct][0], 0, 0, 0);
            acc[ct][1] = __builtin_amdgcn_mfma_f32_32x32x16_f16(ql[ct], pl1, acc[ct][1], 0, 0, 0);
        }
    }

    // Epilogue: Gamma = 2^acc, store gws[c][b].
    // C/D layout (m101, HW-verified): col=lane&31 (b), row = (g&3)+8*(g>>2)+4*(lane>>5) (c)
    const int crow_off = hi ? 4 : 0;
#pragma unroll
    for (int ct = 0; ct < 4; ++ct)
#pragma unroll
        for (int bt = 0; bt < 2; ++bt)
#pragma unroll
            for (int g = 0; g < 16; ++g) {
                float a = acc[ct][bt][g];
                float gm;
                asm("v_exp_f32 %0, %1" : "=v"(gm) : "v"(a));
                int c = ct * 32 + (g & 3) + 8 * (g >> 2) + crow_off;
                gws[(size_t)c * B_N + (b0 + bt * 32 + col)] = gm;
            }
}

// ---------------------------------------------------------------------------
// Finalize: 4 waves per 64 rows; each wave scans a 32-cluster chunk, LDS
// combine. d_out (float32): [B*K scores][B preds][B clusters]
// ---------------------------------------------------------------------------
__global__ __launch_bounds__(256) void k_final(const float* __restrict__ gws,
                                               const int* __restrict__ cls,
                                               float* __restrict__ out) {
    __shared__ float comb[4][64][16];   // [chunk][row][sum,gmax,amax,acc0..9]
    int tid   = threadIdx.x;
    int lane  = tid & 63;               // row within block
    int chunk = tid >> 6;               // wave id = c-chunk
    int b0 = blockIdx.x * 64;
    int b  = b0 + lane;

    float s = 0.f, gmax = -1.f;
    int amax = 0;
    float a0 = 0, a1 = 0, a2 = 0, a3 = 0, a4 = 0, a5 = 0, a6 = 0, a7 = 0, a8 = 0, a9 = 0;
    int cbase = chunk * 32;
    for (int i = 0; i < 32; ++i) {
        int c = cbase + i;
        float g = gws[(size_t)c * B_N + b];     // 256B coalesced per wave
        s += g;
        if (g > gmax) { gmax = g; amax = c; }
        int cl = cls[c];                        // wave-uniform scalar
        if      (cl == 0) a0 += g;
        else if (cl == 1) a1 += g;
        else if (cl == 2) a2 += g;
        else if (cl == 3) a3 += g;
        else if (cl == 4) a4 += g;
        else if (cl == 5) a5 += g;
        else if (cl == 6) a6 += g;
        else if (cl == 7) a7 += g;
        else if (cl == 8) a8 += g;
        else              a9 += g;
    }
    float* cw = comb[chunk][lane];
    cw[0] = s; cw[1] = gmax; cw[2] = (float)amax;
    cw[3] = a0; cw[4] = a1; cw[5] = a2; cw[6] = a3; cw[7] = a4;
    cw[8] = a5; cw[9] = a6; cw[10] = a7; cw[11] = a8; cw[12] = a9;
    __syncthreads();

    if (tid < 64) {
        int row = tid;
        float sum = 0.f, gm = -1.f;
        int am = 0;
        float acc[K_N];
#pragma unroll
        for (int k = 0; k < K_N; ++k) acc[k] = 0.f;
#pragma unroll
        for (int ch = 0; ch < 4; ++ch) {
            const float* cr = comb[ch][row];
            sum += cr[0];
            if (cr[1] > gm) { gm = cr[1]; am = (int)cr[2]; }
#pragma unroll
            for (int k = 0; k < K_N; ++k) acc[k] += cr[3 + k];
        }
        float den = sum + EPS_F;
        float inv = 1.0f / den;
        float best = -1.f;
        int bk = 0;
        float ls[K_N];
#pragma unroll
        for (int k = 0; k < K_N; ++k) {
            ls[k] = acc[k] * inv;
            if (ls[k] > best) { best = ls[k]; bk = k; }
        }
        int bb = b0 + row;
#pragma unroll
        for (int k = 0; k < K_N; ++k) out[(size_t)bb * K_N + k] = ls[k];
        out[(size_t)B_N * K_N + bb] = (float)bk;
        out[(size_t)B_N * K_N + B_N + bb] = (float)am;
    }
}

// ---------------------------------------------------------------------------
extern "C" void kernel_launch(void* const* d_in, const int* in_sizes, int n_in,
                              void* d_out, int out_size, void* d_ws, size_t ws_size,
                              hipStream_t stream) {
    const float* data   = (const float*)d_in[0];   // [B, D]
    const float* mu     = (const float*)d_in[1];   // [C, D]
    const float* S      = (const float*)d_in[2];   // [C, D, D]
    const int*   onehot = (const int*)d_in[3];     // [C, K]
    float* out = (float*)d_out;

    // ws: Gamma [C][B] | Qh [QFRAG_N f16] | Ql [QFRAG_N f16] | Sm [C*D] | t3 [C] | cls [C]
    float*    gws = (float*)d_ws;
    _Float16* Qh  = (_Float16*)(gws + (size_t)C_N * B_N);
    _Float16* Ql  = Qh + QFRAG_N;
    float*    Sm  = (float*)(Ql + QFRAG_N);
    float*    t3  = Sm + C_N * D_N;
    int*      cls = (int*)(t3 + C_N);

    hipLaunchKernelGGL(k_prep_sm, dim3((C_N * D_N) / 256), dim3(256), 0, stream,
                       S, mu, Sm);
    hipLaunchKernelGGL(k_prep_misc, dim3(1), dim3(128), 0, stream,
                       mu, Sm, onehot, t3, cls);
    hipLaunchKernelGGL(k_packfrag, dim3((QFRAG_N + 255) / 256), dim3(256), 0, stream,
                       S, Sm, t3, Qh, Ql);
    hipLaunchKernelGGL(k_mainv2, dim3(B_N / 256), dim3(256), 0, stream,
                       data, Qh, Ql, gws);
    hipLaunchKernelGGL(k_final, dim3(B_N / 64), dim3(256), 0, stream,
                       gws, cls, out);
}

// Round 3
// 127.310 us; speedup vs baseline: 1.2450x; 1.2450x over previous
//
#include <hip/hip_runtime.h>
#include <cmath>

#define B_N 65536
#define C_N 128
#define D_N 32
#define K_N 10
#define EPS_F 1e-12f
#define SCALE_F (-0.72134752044448169f)   // -0.5 * log2(e)

#define NKK 45                   // MFMA K-steps (K = 45*16 = 720 slots, 561 live)
#define QFRAG_N (4 * NKK * 64 * 8)   // 92160 fp16 elements per (hi|lo) array

typedef _Float16 f16x8 __attribute__((ext_vector_type(8)));
typedef float    f32x16 __attribute__((ext_vector_type(16)));

// Window tables: K-step kk covers triangle row pair (WDT[kk], WDT[kk]+1),
// e-window [WET[kk], WET[kk]+8). lane-half (lane>>5) selects which row of the
// pair; slot invalid (Q=0) when d>e or e>32. Last step is row 32 (homog const).
static constexpr int WDT[NKK] = {
    0,0,0,0,0,  2,2,2,2,  4,4,4,4,  6,6,6,6,  8,8,8,8,
    10,10,10, 12,12,12, 14,14,14, 16,16,16,
    18,18, 20,20, 22,22, 24,24, 26, 28, 30, 32};
static constexpr int WET[NKK] = {
    0,8,16,24,32,  2,10,18,26,  4,12,20,28,  6,14,22,30,  8,16,24,32,
    10,18,26, 12,20,28, 14,22,30, 16,24,32,
    18,26, 20,28, 22,30, 24,32, 26, 28, 30, 32};

// ---------------------------------------------------------------------------
// Prep 1: Sm[c][d] = sum_e S_inv[c][d][e] * mu[c][e]
// ---------------------------------------------------------------------------
__global__ __launch_bounds__(256) void k_prep_sm(const float* __restrict__ S,
                                                 const float* __restrict__ mu,
                                                 float* __restrict__ Sm) {
    int t = blockIdx.x * 256 + threadIdx.x;     // 0..4095
    int c = t >> 5;
    int d = t & 31;
    const float* Sr = S + (size_t)c * (D_N * D_N) + (size_t)d * D_N;
    const float* mr = mu + (size_t)c * D_N;
    float a0 = 0.f, a1 = 0.f, a2 = 0.f, a3 = 0.f;
#pragma unroll
    for (int e = 0; e < D_N; e += 4) {
        a0 = fmaf(Sr[e + 0], mr[e + 0], a0);
        a1 = fmaf(Sr[e + 1], mr[e + 1], a1);
        a2 = fmaf(Sr[e + 2], mr[e + 2], a2);
        a3 = fmaf(Sr[e + 3], mr[e + 3], a3);
    }
    Sm[t] = (a0 + a1) + (a2 + a3);
}

// ---------------------------------------------------------------------------
// Prep 2: t3[c] = mu[c].Sm[c];  cls[c] = argmax_k onehot[c][k]
// ---------------------------------------------------------------------------
__global__ __launch_bounds__(128) void k_prep_misc(const float* __restrict__ mu,
                                                   const float* __restrict__ Sm,
                                                   const int* __restrict__ onehot,
                                                   float* __restrict__ t3,
                                                   int* __restrict__ cls) {
    int c = threadIdx.x;
    const float* mr = mu + (size_t)c * D_N;
    const float* sr = Sm + (size_t)c * D_N;
    float a = 0.f;
#pragma unroll
    for (int d = 0; d < D_N; ++d) a = fmaf(mr[d], sr[d], a);
    t3[c] = a;
    int cl = 0;
#pragma unroll
    for (int k = 0; k < K_N; ++k)
        if (onehot[c * K_N + k] != 0) cl = k;
    cls[c] = cl;
}

// ---------------------------------------------------------------------------
// Prep 3: pack Q fragments in MFMA A-operand order, fp16 hi/lo split.
// Element t = ((ct*NKK + kk)*64 + lane)*8 + j holds Q[c = ct*32 + (lane&31)]
// for feature (d = 2r + (lane>>5), e = e0 + j) of K-step kk.
// ---------------------------------------------------------------------------
__global__ __launch_bounds__(256) void k_packfrag(const float* __restrict__ S,
                                                  const float* __restrict__ Sm,
                                                  const float* __restrict__ t3,
                                                  _Float16* __restrict__ Qh,
                                                  _Float16* __restrict__ Ql) {
    int t = blockIdx.x * 256 + threadIdx.x;
    if (t >= QFRAG_N) return;
    int j    = t & 7;
    int lane = (t >> 3) & 63;
    int rest = t >> 9;            // ct*NKK + kk
    int kk   = rest % NKK;
    int ct   = rest / NKK;
    // decode window: r such that kk falls in row-pair r's window list
    int r = 0, base = 0;
    for (;;) {
        int w = (40 - 2 * r) >> 3;          // windows for pair r (r=16 -> 1)
        if (kk < base + w) break;
        base += w; ++r;
    }
    int e0 = 2 * r + 8 * (kk - base);
    int d  = 2 * r + (lane >> 5);
    int e  = e0 + j;
    int c  = ct * 32 + (lane & 31);
    float q = 0.f;
    if (d <= e && e <= 32) {
        float v;
        if (e < 32)      v = S[(size_t)c * (D_N * D_N) + d * D_N + e] * (d == e ? 1.f : 2.f);
        else if (d < 32) v = -2.f * Sm[c * D_N + d];
        else             v = t3[c];
        q = SCALE_F * v;
    }
    _Float16 h = (_Float16)q;
    Qh[t] = h;
    Ql[t] = (_Float16)(q - (float)h);
}

// ---------------------------------------------------------------------------
// Main v3: fused GEMM + finalize.
// Wave owns 32 b-rows x ALL 128 c (4 A-tiles), 3 sections (qh*ph, ql*ph, qh*pl).
// Grid 512 blocks -> 2 blocks/CU -> 2 waves/SIMD (cross-wave VALU/MFMA overlap).
// Per-kk raw s_barrier keeps block's 4 waves on the same Q chunk (L1 reuse);
// Q frags register double-buffered so loads stay in flight across the barrier.
// Epilogue: Gamma never leaves registers -> sum / argmax / per-class sums
// per lane, shfl_xor(32) pair combine, write final outputs directly.
// ---------------------------------------------------------------------------
__global__ __launch_bounds__(256, 2) void k_mainv3(const float* __restrict__ data,
                                                   const _Float16* __restrict__ Qhp,
                                                   const _Float16* __restrict__ Qlp,
                                                   const int* __restrict__ clsp,
                                                   float* __restrict__ out) {
    const int lane = threadIdx.x & 63;
    const int wid  = threadIdx.x >> 6;
    const int b0w  = blockIdx.x * 128 + wid * 32;   // wave's first row
    const int col  = lane & 31;
    const bool hi  = lane >= 32;

    __shared__ int lcls[C_N];
    if (threadIdx.x < C_N) lcls[threadIdx.x] = clsp[threadIdx.x];

    // y for the lane's row (b0w+col); [32]=1 homog, [33]=0 pad
    float y[34];
    {
        const float4* p0 = (const float4*)(data + (size_t)(b0w + col) * D_N);
#pragma unroll
        for (int i = 0; i < 8; ++i) {
            float4 v = p0[i];
            y[4 * i + 0] = v.x; y[4 * i + 1] = v.y;
            y[4 * i + 2] = v.z; y[4 * i + 3] = v.w;
        }
        y[32] = 1.f; y[33] = 0.f;
    }
    __syncthreads();                               // lcls visible; drains y loads

    f32x16 acc[4];
#pragma unroll
    for (int ct = 0; ct < 4; ++ct)
#pragma unroll
        for (int g = 0; g < 16; ++g) acc[ct][g] = 0.f;

    const f16x8* QH = (const f16x8*)Qhp;
    const f16x8* QL = (const f16x8*)Qlp;

    // register double-buffer for Q fragments
    f16x8 qh[2][4], ql[2][4];
#pragma unroll
    for (int ct = 0; ct < 4; ++ct) {
        qh[0][ct] = QH[(ct * NKK + 0) * 64 + lane];
        ql[0][ct] = QL[(ct * NKK + 0) * 64 + lane];
    }

#pragma unroll
    for (int kk = 0; kk < NKK; ++kk) {
        const int cur = kk & 1;          // compile-time under full unroll
        const int nxt = cur ^ 1;
        if (kk + 1 < NKK) {
#pragma unroll
            for (int ct = 0; ct < 4; ++ct) {
                qh[nxt][ct] = QH[(ct * NKK + kk + 1) * 64 + lane];
                ql[nxt][ct] = QL[(ct * NKK + kk + 1) * 64 + lane];
            }
        }

        // B fragment: phi, fp16 hi/lo split (lane's own y[] only)
        const int dA = WDT[kk];
        const int dB = dA + 1;           // <= 33 (y[33]=0)
        const int e0 = WET[kk];
        const float yd = hi ? y[dB] : y[dA];
        f16x8 ph, pl;
#pragma unroll
        for (int j = 0; j < 8; ++j) {
            const int e = e0 + j;
            float f = (e <= 32) ? yd * y[e] : 0.f;
            _Float16 h = (_Float16)f;
            ph[j] = h;
            pl[j] = (_Float16)(f - (float)h);
        }

        // 12 MFMAs: 4 c-tiles x 3 sections, section-major (4 indep chains)
#pragma unroll
        for (int ct = 0; ct < 4; ++ct)
            acc[ct] = __builtin_amdgcn_mfma_f32_32x32x16_f16(qh[cur][ct], ph, acc[ct], 0, 0, 0);
#pragma unroll
        for (int ct = 0; ct < 4; ++ct)
            acc[ct] = __builtin_amdgcn_mfma_f32_32x32x16_f16(ql[cur][ct], ph, acc[ct], 0, 0, 0);
#pragma unroll
        for (int ct = 0; ct < 4; ++ct)
            acc[ct] = __builtin_amdgcn_mfma_f32_32x32x16_f16(qh[cur][ct], pl, acc[ct], 0, 0, 0);

        __builtin_amdgcn_s_barrier();    // pace waves for L1 Q reuse (no drain)
    }

    // ---------------- fused finalize (Gamma stays in registers) --------------
    // C/D layout (HW-verified): col=lane&31 (b), c = ct*32+(g&3)+8*(g>>2)+4*hi
    const float hoff = hi ? 4.f : 0.f;
    const int* lc = lcls + (hi ? 4 : 0);
    float sum = 0.f, gmax = -1.f, gcf = 0.f;
    float a0 = 0, a1 = 0, a2 = 0, a3 = 0, a4 = 0, a5 = 0, a6 = 0, a7 = 0, a8 = 0, a9 = 0;
#pragma unroll
    for (int ct = 0; ct < 4; ++ct) {
        float psum = 0.f;
#pragma unroll
        for (int g = 0; g < 16; ++g) {
            float v = acc[ct][g];
            float gm;
            asm("v_exp_f32 %0, %1" : "=v"(gm) : "v"(v));   // 2^v = exp(-0.5 d2)
            const int cbase = ct * 32 + (g & 3) + 8 * (g >> 2);
            int cl = lc[cbase];                 // LDS broadcast read
            psum += gm;
            float cf = (float)cbase + hoff;
            if (gm > gmax) { gmax = gm; gcf = cf; }   // lane scans c ascending
            a0 += (cl == 0) ? gm : 0.f;
            a1 += (cl == 1) ? gm : 0.f;
            a2 += (cl == 2) ? gm : 0.f;
            a3 += (cl == 3) ? gm : 0.f;
            a4 += (cl == 4) ? gm : 0.f;
            a5 += (cl == 5) ? gm : 0.f;
            a6 += (cl == 6) ? gm : 0.f;
            a7 += (cl == 7) ? gm : 0.f;
            a8 += (cl == 8) ? gm : 0.f;
            a9 += (cl == 9) ? gm : 0.f;
        }
        sum += psum;
    }

    // combine lane pair (l, l+32): same b-row, complementary c halves
    sum += __shfl_xor(sum, 32, 64);
    {
        float om = __shfl_xor(gmax, 32, 64);
        float oc = __shfl_xor(gcf, 32, 64);
        bool take = (om > gmax) || (om == gmax && oc < gcf);  // first-index tie
        if (take) { gmax = om; gcf = oc; }
    }
    a0 += __shfl_xor(a0, 32, 64);
    a1 += __shfl_xor(a1, 32, 64);
    a2 += __shfl_xor(a2, 32, 64);
    a3 += __shfl_xor(a3, 32, 64);
    a4 += __shfl_xor(a4, 32, 64);
    a5 += __shfl_xor(a5, 32, 64);
    a6 += __shfl_xor(a6, 32, 64);
    a7 += __shfl_xor(a7, 32, 64);
    a8 += __shfl_xor(a8, 32, 64);
    a9 += __shfl_xor(a9, 32, 64);

    if (!hi) {
        const int b = b0w + col;
        float inv = 1.0f / (sum + EPS_F);
        float ls[K_N] = {a0 * inv, a1 * inv, a2 * inv, a3 * inv, a4 * inv,
                         a5 * inv, a6 * inv, a7 * inv, a8 * inv, a9 * inv};
        float best = -1.f;
        int bk = 0;
#pragma unroll
        for (int k = 0; k < K_N; ++k)
            if (ls[k] > best) { best = ls[k]; bk = k; }
        float2* o2 = (float2*)(out + (size_t)b * K_N);   // b*40B is 8B-aligned
#pragma unroll
        for (int k2 = 0; k2 < K_N / 2; ++k2)
            o2[k2] = make_float2(ls[2 * k2], ls[2 * k2 + 1]);
        out[(size_t)B_N * K_N + b] = (float)bk;
        out[(size_t)B_N * K_N + B_N + b] = gcf;
    }
}

// ---------------------------------------------------------------------------
extern "C" void kernel_launch(void* const* d_in, const int* in_sizes, int n_in,
                              void* d_out, int out_size, void* d_ws, size_t ws_size,
                              hipStream_t stream) {
    const float* data   = (const float*)d_in[0];   // [B, D]
    const float* mu     = (const float*)d_in[1];   // [C, D]
    const float* S      = (const float*)d_in[2];   // [C, D, D]
    const int*   onehot = (const int*)d_in[3];     // [C, K]
    float* out = (float*)d_out;

    // ws: Qh [QFRAG_N f16] | Ql [QFRAG_N f16] | Sm [C*D] | t3 [C] | cls [C]
    _Float16* Qh  = (_Float16*)d_ws;
    _Float16* Ql  = Qh + QFRAG_N;
    float*    Sm  = (float*)(Ql + QFRAG_N);
    float*    t3  = Sm + C_N * D_N;
    int*      cls = (int*)(t3 + C_N);

    hipLaunchKernelGGL(k_prep_sm, dim3((C_N * D_N) / 256), dim3(256), 0, stream,
                       S, mu, Sm);
    hipLaunchKernelGGL(k_prep_misc, dim3(1), dim3(128), 0, stream,
                       mu, Sm, onehot, t3, cls);
    hipLaunchKernelGGL(k_packfrag, dim3((QFRAG_N + 255) / 256), dim3(256), 0, stream,
                       S, Sm, t3, Qh, Ql);
    hipLaunchKernelGGL(k_mainv3, dim3(B_N / 128), dim3(256), 0, stream,
                       data, Qh, Ql, cls, out);
}

// Round 4
// 126.030 us; speedup vs baseline: 1.2576x; 1.0102x over previous
//
#include <hip/hip_runtime.h>
#include <cmath>

#define B_N 65536
#define C_N 128
#define D_N 32
#define K_N 10
#define EPS_F 1e-12f
#define SCALE_F (-0.72134752044448169f)   // -0.5 * log2(e)

#define NKK 45                   // MFMA K-steps (K = 45*16 = 720 slots, 561 live)
#define QFRAG_N (4 * NKK * 64 * 8)   // 92160 fp16 elements per (hi|lo) array

typedef _Float16 f16x8 __attribute__((ext_vector_type(8)));
typedef float    f32x16 __attribute__((ext_vector_type(16)));

// Window tables: K-step kk covers triangle row pair (WDT[kk], WDT[kk]+1),
// e-window [WET[kk], WET[kk]+8). lane-half (lane>>5) selects row of the pair;
// slot invalid (Q=0) when d>e or e>32. Last step is row 32 (homog const).
static constexpr int WDT[NKK] = {
    0,0,0,0,0,  2,2,2,2,  4,4,4,4,  6,6,6,6,  8,8,8,8,
    10,10,10, 12,12,12, 14,14,14, 16,16,16,
    18,18, 20,20, 22,22, 24,24, 26, 28, 30, 32};
static constexpr int WET[NKK] = {
    0,8,16,24,32,  2,10,18,26,  4,12,20,28,  6,14,22,30,  8,16,24,32,
    10,18,26, 12,20,28, 14,22,30, 16,24,32,
    18,26, 20,28, 22,30, 24,32, 26, 28, 30, 32};

// ---------------------------------------------------------------------------
// Fused prep: block = cluster c (128 blocks x 128 threads).
//   phase 1: sSm[d] = sum_e S[c][d][e]*mu[c][e]          (32 threads)
//   phase 2: t3 = mu.sSm; cls[c] = argmax onehot          (thread 0)
//   phase 3: pack Q fragments (fp16 hi/lo) for this c     (90 threads: kk x half)
// Frag element t = ((ct*NKK+kk)*64 + lane)*8 + j, lane = half*32 + (c&31),
// holds Q[c] for feature (d = WDT[kk]+half, e = WET[kk]+j).
// ---------------------------------------------------------------------------
__global__ __launch_bounds__(128) void k_prep(const float* __restrict__ S,
                                              const float* __restrict__ mu,
                                              const int* __restrict__ onehot,
                                              _Float16* __restrict__ Qh,
                                              _Float16* __restrict__ Ql,
                                              int* __restrict__ cls) {
    const int c = blockIdx.x;
    const int tid = threadIdx.x;
    __shared__ float sSm[D_N];
    __shared__ float st3;

    if (tid < D_N) {
        const float* Sr = S + (size_t)c * (D_N * D_N) + (size_t)tid * D_N;
        const float* mr = mu + (size_t)c * D_N;
        float a0 = 0.f, a1 = 0.f;
#pragma unroll
        for (int e = 0; e < D_N; e += 2) {
            a0 = fmaf(Sr[e + 0], mr[e + 0], a0);
            a1 = fmaf(Sr[e + 1], mr[e + 1], a1);
        }
        sSm[tid] = a0 + a1;
    }
    __syncthreads();
    if (tid == 0) {
        const float* mr = mu + (size_t)c * D_N;
        float a = 0.f;
#pragma unroll
        for (int d = 0; d < D_N; ++d) a = fmaf(mr[d], sSm[d], a);
        st3 = a;
        int cl = 0;
#pragma unroll
        for (int k = 0; k < K_N; ++k)
            if (onehot[c * K_N + k] != 0) cl = k;
        cls[c] = cl;
    }
    __syncthreads();

    if (tid < 2 * NKK) {
        const int kk   = tid >> 1;
        const int half = tid & 1;
        const int e0 = WET[kk];
        const int d  = WDT[kk] + half;        // may be 33 (invalid -> q=0)
        const int ct = c >> 5;
        const size_t base =
            ((size_t)(ct * NKK + kk) * 64 + half * 32 + (c & 31)) * 8;
        const float* Sc = S + (size_t)c * (D_N * D_N);
        for (int j = 0; j < 8; ++j) {
            const int e = e0 + j;
            float q = 0.f;
            if (d <= e && e <= 32) {
                float v;
                if (e < 32)      v = Sc[d * D_N + e] * (d == e ? 1.f : 2.f);
                else if (d < 32) v = -2.f * sSm[d];
                else             v = st3;          // d == e == 32
                q = SCALE_F * v;
            }
            _Float16 h = (_Float16)q;
            Qh[base + j] = h;
            Ql[base + j] = (_Float16)(q - (float)h);
        }
    }
}

// ---------------------------------------------------------------------------
// Main v4 K-step: COMPILE-TIME KK via template recursion so every array index
// (Q double-buffer kk&1, y[e], window tables) is static by construction --
// no possibility of scratch demotion (rule #20; v3's VGPR=68 smoking gun).
// ---------------------------------------------------------------------------
template <int KK>
__device__ __forceinline__ void kstep(const f16x8* __restrict__ QH,
                                      const f16x8* __restrict__ QL,
                                      int lane, bool hi, const float (&y)[34],
                                      f16x8 (&bh)[2][4], f16x8 (&bl)[2][4],
                                      f32x16 (&acc)[4]) {
    constexpr int cur = KK & 1;
    constexpr int nxt = cur ^ 1;
    if constexpr (KK + 1 < NKK) {       // prefetch next-step fragments
#pragma unroll
        for (int ct = 0; ct < 4; ++ct) {
            bh[nxt][ct] = QH[(ct * NKK + KK + 1) * 64 + lane];
            bl[nxt][ct] = QL[(ct * NKK + KK + 1) * 64 + lane];
        }
    }
    constexpr int dA = WDT[KK];
    constexpr int e0 = WET[KK];
    const float yd = hi ? y[dA + 1] : y[dA];    // dA+1 <= 33 (y[33]=0)
    f16x8 ph, pl;
#pragma unroll
    for (int j = 0; j < 8; ++j) {               // literal bound: always unrolled
        float f = (e0 + j <= 32) ? yd * y[e0 + j] : 0.f;
        _Float16 h = (_Float16)f;
        ph[j] = h;
        pl[j] = (_Float16)(f - (float)h);
    }
    // 12 MFMAs: 3 sections x 4 c-tiles (4 independent acc chains per section)
#pragma unroll
    for (int ct = 0; ct < 4; ++ct)
        acc[ct] = __builtin_amdgcn_mfma_f32_32x32x16_f16(bh[cur][ct], ph, acc[ct], 0, 0, 0);
#pragma unroll
    for (int ct = 0; ct < 4; ++ct)
        acc[ct] = __builtin_amdgcn_mfma_f32_32x32x16_f16(bl[cur][ct], ph, acc[ct], 0, 0, 0);
#pragma unroll
    for (int ct = 0; ct < 4; ++ct)
        acc[ct] = __builtin_amdgcn_mfma_f32_32x32x16_f16(bh[cur][ct], pl, acc[ct], 0, 0, 0);
}

template <int KK>
__device__ __forceinline__ void loop_from(const f16x8* __restrict__ QH,
                                          const f16x8* __restrict__ QL,
                                          int lane, bool hi, const float (&y)[34],
                                          f16x8 (&bh)[2][4], f16x8 (&bl)[2][4],
                                          f32x16 (&acc)[4]) {
    if constexpr (KK < NKK) {
        kstep<KK>(QH, QL, lane, hi, y, bh, bl, acc);
        loop_from<KK + 1>(QH, QL, lane, hi, y, bh, bl, acc);
    }
}

// ---------------------------------------------------------------------------
// Main v4: fused GEMM + finalize. Wave owns 32 b-rows x all 128 c (4 A-tiles),
// 3 fp16-pair sections. Grid 512 -> 2 blocks/CU -> 2 waves/SIMD. No in-loop
// barriers (free-running waves; Q is L2-resident, 188 MB ~ 5.5 us floor).
// Epilogue: Gamma stays in registers -> sum/argmax/per-class sums per lane,
// shfl_xor(32) pair combine, final outputs written directly.
// ---------------------------------------------------------------------------
__global__ __launch_bounds__(256, 2) void k_mainv4(const float* __restrict__ data,
                                                   const _Float16* __restrict__ Qhp,
                                                   const _Float16* __restrict__ Qlp,
                                                   const int* __restrict__ clsp,
                                                   float* __restrict__ out) {
    const int lane = threadIdx.x & 63;
    const int wid  = threadIdx.x >> 6;
    const int b0w  = blockIdx.x * 128 + wid * 32;   // wave's first row
    const int col  = lane & 31;
    const bool hi  = lane >= 32;

    __shared__ int lcls[C_N];
    if (threadIdx.x < C_N) lcls[threadIdx.x] = clsp[threadIdx.x];

    // y for the lane's row (b0w+col); [32]=1 homog, [33]=0 pad
    float y[34];
    {
        const float4* p0 = (const float4*)(data + (size_t)(b0w + col) * D_N);
#pragma unroll
        for (int i = 0; i < 8; ++i) {
            float4 v = p0[i];
            y[4 * i + 0] = v.x; y[4 * i + 1] = v.y;
            y[4 * i + 2] = v.z; y[4 * i + 3] = v.w;
        }
        y[32] = 1.f; y[33] = 0.f;
    }
    __syncthreads();                               // lcls visible

    f32x16 acc[4];
#pragma unroll
    for (int ct = 0; ct < 4; ++ct)
#pragma unroll
        for (int g = 0; g < 16; ++g) acc[ct][g] = 0.f;

    const f16x8* QH = (const f16x8*)Qhp;
    const f16x8* QL = (const f16x8*)Qlp;

    f16x8 bh[2][4], bl[2][4];                      // register double-buffer
#pragma unroll
    for (int ct = 0; ct < 4; ++ct) {
        bh[0][ct] = QH[(ct * NKK + 0) * 64 + lane];
        bl[0][ct] = QL[(ct * NKK + 0) * 64 + lane];
    }

    loop_from<0>(QH, QL, lane, hi, y, bh, bl, acc);

    // ---------------- fused finalize (Gamma stays in registers) --------------
    // C/D layout (HW-verified): col=lane&31 (b), c = ct*32+(g&3)+8*(g>>2)+4*hi
    const float hoff = hi ? 4.f : 0.f;
    const int* lc = lcls + (hi ? 4 : 0);
    float sum = 0.f, gmax = -1.f, gcf = 0.f;
    float a0 = 0, a1 = 0, a2 = 0, a3 = 0, a4 = 0, a5 = 0, a6 = 0, a7 = 0, a8 = 0, a9 = 0;
#pragma unroll
    for (int ct = 0; ct < 4; ++ct) {
        float psum = 0.f;
#pragma unroll
        for (int g = 0; g < 16; ++g) {
            float v = acc[ct][g];
            float gm;
            asm("v_exp_f32 %0, %1" : "=v"(gm) : "v"(v));   // 2^v = exp(-0.5 d2)
            const int cbase = ct * 32 + (g & 3) + 8 * (g >> 2);
            int cl = lc[cbase];                 // LDS broadcast read
            psum += gm;
            float cf = (float)cbase + hoff;
            if (gm > gmax) { gmax = gm; gcf = cf; }   // lane scans c ascending
            a0 += (cl == 0) ? gm : 0.f;
            a1 += (cl == 1) ? gm : 0.f;
            a2 += (cl == 2) ? gm : 0.f;
            a3 += (cl == 3) ? gm : 0.f;
            a4 += (cl == 4) ? gm : 0.f;
            a5 += (cl == 5) ? gm : 0.f;
            a6 += (cl == 6) ? gm : 0.f;
            a7 += (cl == 7) ? gm : 0.f;
            a8 += (cl == 8) ? gm : 0.f;
            a9 += (cl == 9) ? gm : 0.f;
        }
        sum += psum;
    }

    // combine lane pair (l, l+32): same b-row, complementary c halves
    sum += __shfl_xor(sum, 32, 64);
    {
        float om = __shfl_xor(gmax, 32, 64);
        float oc = __shfl_xor(gcf, 32, 64);
        bool take = (om > gmax) || (om == gmax && oc < gcf);  // first-index tie
        if (take) { gmax = om; gcf = oc; }
    }
    a0 += __shfl_xor(a0, 32, 64);
    a1 += __shfl_xor(a1, 32, 64);
    a2 += __shfl_xor(a2, 32, 64);
    a3 += __shfl_xor(a3, 32, 64);
    a4 += __shfl_xor(a4, 32, 64);
    a5 += __shfl_xor(a5, 32, 64);
    a6 += __shfl_xor(a6, 32, 64);
    a7 += __shfl_xor(a7, 32, 64);
    a8 += __shfl_xor(a8, 32, 64);
    a9 += __shfl_xor(a9, 32, 64);

    if (!hi) {
        const int b = b0w + col;
        float inv = 1.0f / (sum + EPS_F);
        float ls[K_N] = {a0 * inv, a1 * inv, a2 * inv, a3 * inv, a4 * inv,
                         a5 * inv, a6 * inv, a7 * inv, a8 * inv, a9 * inv};
        float best = -1.f;
        int bk = 0;
#pragma unroll
        for (int k = 0; k < K_N; ++k)
            if (ls[k] > best) { best = ls[k]; bk = k; }
        float2* o2 = (float2*)(out + (size_t)b * K_N);   // b*40B is 8B-aligned
#pragma unroll
        for (int k2 = 0; k2 < K_N / 2; ++k2)
            o2[k2] = make_float2(ls[2 * k2], ls[2 * k2 + 1]);
        out[(size_t)B_N * K_N + b] = (float)bk;
        out[(size_t)B_N * K_N + B_N + b] = gcf;
    }
}

// ---------------------------------------------------------------------------
extern "C" void kernel_launch(void* const* d_in, const int* in_sizes, int n_in,
                              void* d_out, int out_size, void* d_ws, size_t ws_size,
                              hipStream_t stream) {
    const float* data   = (const float*)d_in[0];   // [B, D]
    const float* mu     = (const float*)d_in[1];   // [C, D]
    const float* S      = (const float*)d_in[2];   // [C, D, D]
    const int*   onehot = (const int*)d_in[3];     // [C, K]
    float* out = (float*)d_out;

    // ws: Qh [QFRAG_N f16] | Ql [QFRAG_N f16] | cls [C]
    _Float16* Qh  = (_Float16*)d_ws;
    _Float16* Ql  = Qh + QFRAG_N;
    int*      cls = (int*)(Ql + QFRAG_N);

    hipLaunchKernelGGL(k_prep, dim3(C_N), dim3(128), 0, stream,
                       S, mu, onehot, Qh, Ql, cls);
    hipLaunchKernelGGL(k_mainv4, dim3(B_N / 128), dim3(256), 0, stream,
                       data, Qh, Ql, cls, out);
}

// Round 5
// 114.296 us; speedup vs baseline: 1.3867x; 1.1027x over previous
//
#include <hip/hip_runtime.h>
#include <cmath>

#define B_N 65536
#define C_N 128
#define D_N 32
#define K_N 10
#define EPS_F 1e-12f
#define SCALE_F (-0.72134752044448169f)   // -0.5 * log2(e)

#define NKK 48                   // K-steps (45 live + 3 zero pad), K = 768 slots
#define QFRAG_N (4 * NKK * 64 * 8)   // 98304 fp16 elements per (hi|lo) array
#define YSTR 41                  // LDS y row stride (41: lane*41%32 walks all banks)

typedef _Float16 f16x8 __attribute__((ext_vector_type(8)));
typedef float    f32x16 __attribute__((ext_vector_type(16)));

// Step order is (window w, row-pair r) so metadata is AFFINE (no tables):
//   kk -> w = #{thresholds <= kk}, r = kk - off[w];  dA = 2r, e0 = 2r + 8w.
// Live steps kk<45 cover the packed triangle exactly once; kk=45..47 are
// zero-Q pad. Windows with e>32 have Q=0 (and y LDS rows are zero there).
__device__ __forceinline__ void mdkk(int kk, int& dA, int& e0) {
    int w = (kk >= 17) + (kk >= 30) + (kk >= 39) + (kk >= 44);
    int off = w == 0 ? 0 : (w == 1 ? 17 : (w == 2 ? 30 : (w == 3 ? 39 : 44)));
    int r = kk - off;
    dA = 2 * r;
    e0 = 2 * r + 8 * w;
}

// ---------------------------------------------------------------------------
// Fused prep: block = cluster c (128 blocks x 128 threads).
//   phase 1: sSm[d] = sum_e S[c][d][e]*mu[c][e]
//   phase 2: t3 = mu.sSm; cls[c]
//   phase 3: pack Q fragments (fp16 hi/lo) for this c (96 threads: kk x half)
// Frag element t = ((ct*NKK+kk)*64 + half*32 + (c&31))*8 + j holds Q[c] for
// feature (d = dA(kk)+half, e = e0(kk)+j); 0 unless d<=e<=32.
// ---------------------------------------------------------------------------
__global__ __launch_bounds__(128) void k_prep(const float* __restrict__ S,
                                              const float* __restrict__ mu,
                                              const int* __restrict__ onehot,
                                              _Float16* __restrict__ Qh,
                                              _Float16* __restrict__ Ql,
                                              int* __restrict__ cls) {
    const int c = blockIdx.x;
    const int tid = threadIdx.x;
    __shared__ float sSm[D_N];
    __shared__ float st3;

    if (tid < D_N) {
        const float* Sr = S + (size_t)c * (D_N * D_N) + (size_t)tid * D_N;
        const float* mr = mu + (size_t)c * D_N;
        float a0 = 0.f, a1 = 0.f;
#pragma unroll
        for (int e = 0; e < D_N; e += 2) {
            a0 = fmaf(Sr[e + 0], mr[e + 0], a0);
            a1 = fmaf(Sr[e + 1], mr[e + 1], a1);
        }
        sSm[tid] = a0 + a1;
    }
    __syncthreads();
    if (tid == 0) {
        const float* mr = mu + (size_t)c * D_N;
        float a = 0.f;
#pragma unroll
        for (int d = 0; d < D_N; ++d) a = fmaf(mr[d], sSm[d], a);
        st3 = a;
        int cl = 0;
#pragma unroll
        for (int k = 0; k < K_N; ++k)
            if (onehot[c * K_N + k] != 0) cl = k;
        cls[c] = cl;
    }
    __syncthreads();

    if (tid < 2 * NKK) {
        const int kk   = tid >> 1;
        const int half = tid & 1;
        int dA, e0;
        mdkk(kk, dA, e0);
        const int d  = dA + half;
        const int ct = c >> 5;
        const size_t base =
            ((size_t)(ct * NKK + kk) * 64 + half * 32 + (c & 31)) * 8;
        const float* Sc = S + (size_t)c * (D_N * D_N);
        for (int j = 0; j < 8; ++j) {
            const int e = e0 + j;
            float q = 0.f;
            if (d <= e && e <= 32) {
                float v;
                if (e < 32)      v = Sc[d * D_N + e] * (d == e ? 1.f : 2.f);
                else if (d < 32) v = -2.f * sSm[d];
                else             v = st3;          // d == e == 32
                q = SCALE_F * v;
            }
            _Float16 h = (_Float16)q;
            Qh[base + j] = h;
            Ql[base + j] = (_Float16)(q - (float)h);
        }
    }
}

// ---------------------------------------------------------------------------
// v5 helpers: named-register buffers, all indices literal (no scratch risk).
// ---------------------------------------------------------------------------
__device__ __forceinline__ void ldq(const f16x8* __restrict__ QH,
                                    const f16x8* __restrict__ QL,
                                    int kk, int lane,
                                    f16x8 (&qh)[4], f16x8 (&ql)[4]) {
#pragma unroll
    for (int ct = 0; ct < 4; ++ct) {
        qh[ct] = QH[(ct * NKK + kk) * 64 + lane];
        ql[ct] = QL[(ct * NKK + kk) * 64 + lane];
    }
}

__device__ __forceinline__ void ldy(const float* sy, int ybase, int hioff,
                                    int kk, float& yd, float (&yw)[8]) {
    int dA, e0;
    mdkk(kk, dA, e0);
    yd = sy[ybase + dA + hioff];
#pragma unroll
    for (int j = 0; j < 8; ++j) yw[j] = sy[ybase + e0 + j];
}

__device__ __forceinline__ void domfma(const f16x8 (&qh)[4], const f16x8 (&ql)[4],
                                       float yd, const float (&yw)[8],
                                       f32x16 (&acc)[4]) {
    f16x8 ph, pl;
#pragma unroll
    for (int j = 0; j < 8; ++j) {
        float f = yd * yw[j];
        _Float16 h = (_Float16)f;
        ph[j] = h;
        pl[j] = (_Float16)(f - (float)h);
    }
#pragma unroll
    for (int ct = 0; ct < 4; ++ct)
        acc[ct] = __builtin_amdgcn_mfma_f32_32x32x16_f16(qh[ct], ph, acc[ct], 0, 0, 0);
#pragma unroll
    for (int ct = 0; ct < 4; ++ct)
        acc[ct] = __builtin_amdgcn_mfma_f32_32x32x16_f16(ql[ct], ph, acc[ct], 0, 0, 0);
#pragma unroll
    for (int ct = 0; ct < 4; ++ct)
        acc[ct] = __builtin_amdgcn_mfma_f32_32x32x16_f16(qh[ct], pl, acc[ct], 0, 0, 0);
}

// ---------------------------------------------------------------------------
// Main v5: ROLLED K-loop (16 iters x 3 steps, ~2 KB body; v3/v4's 40 KB
// straight-line code streamed the I$ with zero reuse). y lives in LDS
// (stride 41 -> <=2-way bank aliasing = free), windows prefetched 1 step
// ahead into named regs; Q prefetched ~2.5 steps ahead in a 3-slot rotation
// (covers L2 latency). Metadata is SALU-affine. Epilogue unchanged.
// ---------------------------------------------------------------------------
__global__ __launch_bounds__(256, 2) void k_mainv5(const float* __restrict__ data,
                                                   const _Float16* __restrict__ Qhp,
                                                   const _Float16* __restrict__ Qlp,
                                                   const int* __restrict__ clsp,
                                                   float* __restrict__ out) {
    const int tid  = threadIdx.x;
    const int lane = tid & 63;
    const int wid  = tid >> 6;
    const int b0w  = blockIdx.x * 128 + wid * 32;   // wave's first row
    const int col  = lane & 31;
    const bool hi  = lane >= 32;

    __shared__ float sy[256 * YSTR + 64];
    __shared__ int lcls[C_N];
    if (tid < C_N) lcls[tid] = clsp[tid];

    const int ybase = tid * YSTR;
    {
        const float4* p0 = (const float4*)(data + (size_t)(b0w + col) * D_N);
#pragma unroll
        for (int i = 0; i < 8; ++i) {
            float4 v = p0[i];
            sy[ybase + 4 * i + 0] = v.x;
            sy[ybase + 4 * i + 1] = v.y;
            sy[ybase + 4 * i + 2] = v.z;
            sy[ybase + 4 * i + 3] = v.w;
        }
        sy[ybase + 32] = 1.f;                        // homogeneous slot
#pragma unroll
        for (int i = 33; i < YSTR; ++i) sy[ybase + i] = 0.f;
        if (tid < 64) sy[256 * YSTR + tid] = 0.f;    // tail pad (finite!)
    }
    __syncthreads();

    f32x16 acc[4];
#pragma unroll
    for (int ct = 0; ct < 4; ++ct)
#pragma unroll
        for (int g = 0; g < 16; ++g) acc[ct][g] = 0.f;

    const f16x8* QH = (const f16x8*)Qhp;
    const f16x8* QL = (const f16x8*)Qlp;
    const int hioff = hi ? 1 : 0;

    // 3-slot register rotation
    f16x8 qhA[4], qlA[4], qhB[4], qlB[4], qhC[4], qlC[4];
    float ydA, ywA[8], ydB, ywB[8], ydC, ywC[8];

    ldq(QH, QL, 0, lane, qhA, qlA);
    ldq(QH, QL, 1, lane, qhB, qlB);
    ldq(QH, QL, 2, lane, qhC, qlC);
    ldy(sy, ybase, hioff, 0, ydA, ywA);

#pragma clang loop unroll(disable)
    for (int kk = 0; kk < NKK; kk += 3) {
        // ---- step kk (slot A) ----
        ldy(sy, ybase, hioff, kk + 1, ydB, ywB);              // y for kk+1
        domfma(qhA, qlA, ydA, ywA, acc);
        { int t = kk + 3 < NKK ? kk + 3 : NKK - 1;            // Q for kk+3
          ldq(QH, QL, t, lane, qhA, qlA); }
        // ---- step kk+1 (slot B) ----
        ldy(sy, ybase, hioff, kk + 2, ydC, ywC);              // y for kk+2
        domfma(qhB, qlB, ydB, ywB, acc);
        { int t = kk + 4 < NKK ? kk + 4 : NKK - 1;
          ldq(QH, QL, t, lane, qhB, qlB); }
        // ---- step kk+2 (slot C) ----
        { int t = kk + 3 < NKK ? kk + 3 : NKK - 1;            // y for next sA
          ldy(sy, ybase, hioff, t, ydA, ywA); }
        domfma(qhC, qlC, ydC, ywC, acc);
        { int t = kk + 5 < NKK ? kk + 5 : NKK - 1;
          ldq(QH, QL, t, lane, qhC, qlC); }
    }

    // ---------------- fused finalize (Gamma stays in registers) --------------
    // C/D layout (HW-verified): col=lane&31 (b), c = ct*32+(g&3)+8*(g>>2)+4*hi
    const float hoff = hi ? 4.f : 0.f;
    const int* lc = lcls + (hi ? 4 : 0);
    float sum = 0.f, gmax = -1.f, gcf = 0.f;
    float a0 = 0, a1 = 0, a2 = 0, a3 = 0, a4 = 0, a5 = 0, a6 = 0, a7 = 0, a8 = 0, a9 = 0;
#pragma unroll
    for (int ct = 0; ct < 4; ++ct) {
        float psum = 0.f;
#pragma unroll
        for (int g = 0; g < 16; ++g) {
            float v = acc[ct][g];
            float gm;
            asm("v_exp_f32 %0, %1" : "=v"(gm) : "v"(v));   // 2^v = exp(-0.5 d2)
            const int cbase = ct * 32 + (g & 3) + 8 * (g >> 2);
            int cl = lc[cbase];                 // LDS broadcast read
            psum += gm;
            float cf = (float)cbase + hoff;
            if (gm > gmax) { gmax = gm; gcf = cf; }   // lane scans c ascending
            a0 += (cl == 0) ? gm : 0.f;
            a1 += (cl == 1) ? gm : 0.f;
            a2 += (cl == 2) ? gm : 0.f;
            a3 += (cl == 3) ? gm : 0.f;
            a4 += (cl == 4) ? gm : 0.f;
            a5 += (cl == 5) ? gm : 0.f;
            a6 += (cl == 6) ? gm : 0.f;
            a7 += (cl == 7) ? gm : 0.f;
            a8 += (cl == 8) ? gm : 0.f;
            a9 += (cl == 9) ? gm : 0.f;
        }
        sum += psum;
    }

    // combine lane pair (l, l+32): same b-row, complementary c halves
    sum += __shfl_xor(sum, 32, 64);
    {
        float om = __shfl_xor(gmax, 32, 64);
        float oc = __shfl_xor(gcf, 32, 64);
        bool take = (om > gmax) || (om == gmax && oc < gcf);  // first-index tie
        if (take) { gmax = om; gcf = oc; }
    }
    a0 += __shfl_xor(a0, 32, 64);
    a1 += __shfl_xor(a1, 32, 64);
    a2 += __shfl_xor(a2, 32, 64);
    a3 += __shfl_xor(a3, 32, 64);
    a4 += __shfl_xor(a4, 32, 64);
    a5 += __shfl_xor(a5, 32, 64);
    a6 += __shfl_xor(a6, 32, 64);
    a7 += __shfl_xor(a7, 32, 64);
    a8 += __shfl_xor(a8, 32, 64);
    a9 += __shfl_xor(a9, 32, 64);

    if (!hi) {
        const int b = b0w + col;
        float inv = 1.0f / (sum + EPS_F);
        float ls[K_N] = {a0 * inv, a1 * inv, a2 * inv, a3 * inv, a4 * inv,
                         a5 * inv, a6 * inv, a7 * inv, a8 * inv, a9 * inv};
        float best = -1.f;
        int bk = 0;
#pragma unroll
        for (int k = 0; k < K_N; ++k)
            if (ls[k] > best) { best = ls[k]; bk = k; }
        float2* o2 = (float2*)(out + (size_t)b * K_N);   // b*40B is 8B-aligned
#pragma unroll
        for (int k2 = 0; k2 < K_N / 2; ++k2)
            o2[k2] = make_float2(ls[2 * k2], ls[2 * k2 + 1]);
        out[(size_t)B_N * K_N + b] = (float)bk;
        out[(size_t)B_N * K_N + B_N + b] = gcf;
    }
}

// ---------------------------------------------------------------------------
extern "C" void kernel_launch(void* const* d_in, const int* in_sizes, int n_in,
                              void* d_out, int out_size, void* d_ws, size_t ws_size,
                              hipStream_t stream) {
    const float* data   = (const float*)d_in[0];   // [B, D]
    const float* mu     = (const float*)d_in[1];   // [C, D]
    const float* S      = (const float*)d_in[2];   // [C, D, D]
    const int*   onehot = (const int*)d_in[3];     // [C, K]
    float* out = (float*)d_out;

    // ws: Qh [QFRAG_N f16] | Ql [QFRAG_N f16] | cls [C]
    _Float16* Qh  = (_Float16*)d_ws;
    _Float16* Ql  = Qh + QFRAG_N;
    int*      cls = (int*)(Ql + QFRAG_N);

    hipLaunchKernelGGL(k_prep, dim3(C_N), dim3(128), 0, stream,
                       S, mu, onehot, Qh, Ql, cls);
    hipLaunchKernelGGL(k_mainv5, dim3(B_N / 128), dim3(256), 0, stream,
                       data, Qh, Ql, cls, out);
}

// Round 8
// 106.625 us; speedup vs baseline: 1.4865x; 1.0719x over previous
//
#include <hip/hip_runtime.h>
#include <cmath>

#define B_N 65536
#define C_N 128
#define D_N 32
#define K_N 10
#define EPS_F 1e-12f
#define SCALE_F (-0.72134752044448169f)   // -0.5 * log2(e)

#define NKK 46                    // 45 live K-steps + 1 zero pad (even count)
#define CHUNK_F16 4096            // per-step Q chunk: 4ct x 2hl x 64lane x 8 f16 = 8 KB
#define QF_N (NKK * CHUNK_F16)
#define YSTR 41                   // LDS y row stride (2 lanes/bank aliasing = free)

typedef _Float16 f16x8 __attribute__((ext_vector_type(8)));
typedef float    f32x16 __attribute__((ext_vector_type(16)));

// Step metadata, affine in (window w, row-pair r) order; kk>=45 is the zero-Q
// pad step (clamped to safe y offsets; prep writes Q=0 there).
__device__ __forceinline__ void mdkk(int kk, int& dA, int& e0) {
    if (kk >= 45) { dA = 0; e0 = 0; return; }
    int w = (kk >= 17) + (kk >= 30) + (kk >= 39) + (kk >= 44);
    int off = w == 0 ? 0 : (w == 1 ? 17 : (w == 2 ? 30 : (w == 3 ? 39 : 44)));
    int r = kk - off;
    dA = 2 * r;
    e0 = 2 * r + 8 * w;
}

// ---------------------------------------------------------------------------
// Fused prep: block = cluster c. Packs Q into the STAGING layout:
//   QF[kk*4096 + ct*1024 + hl*512 + (half*32 + (c&31))*8 + j]
// hl=0: fp16 hi, hl=1: fp16 lo. Feature (d = dA(kk)+half, e = e0(kk)+j),
// value SCALE * (2-off-diag folded) as before; 0 unless kk<45 & d<=e<=32.
// ---------------------------------------------------------------------------
__global__ __launch_bounds__(128) void k_prep(const float* __restrict__ S,
                                              const float* __restrict__ mu,
                                              const int* __restrict__ onehot,
                                              _Float16* __restrict__ QF,
                                              int* __restrict__ cls) {
    const int c = blockIdx.x;
    const int tid = threadIdx.x;
    __shared__ float sSm[D_N];
    __shared__ float st3;

    if (tid < D_N) {
        const float* Sr = S + (size_t)c * (D_N * D_N) + (size_t)tid * D_N;
        const float* mr = mu + (size_t)c * D_N;
        float a0 = 0.f, a1 = 0.f;
#pragma unroll
        for (int e = 0; e < D_N; e += 2) {
            a0 = fmaf(Sr[e + 0], mr[e + 0], a0);
            a1 = fmaf(Sr[e + 1], mr[e + 1], a1);
        }
        sSm[tid] = a0 + a1;
    }
    __syncthreads();
    if (tid == 0) {
        const float* mr = mu + (size_t)c * D_N;
        float a = 0.f;
#pragma unroll
        for (int d = 0; d < D_N; ++d) a = fmaf(mr[d], sSm[d], a);
        st3 = a;
        int cl = 0;
#pragma unroll
        for (int k = 0; k < K_N; ++k)
            if (onehot[c * K_N + k] != 0) cl = k;
        cls[c] = cl;
    }
    __syncthreads();

    if (tid < 2 * NKK) {
        const int kk   = tid >> 1;
        const int half = tid & 1;
        int dA, e0;
        mdkk(kk, dA, e0);
        const int d  = dA + half;
        const int ct = c >> 5;
        const size_t base = (size_t)kk * CHUNK_F16 + ct * 1024
                          + (size_t)(half * 32 + (c & 31)) * 8;
        const float* Sc = S + (size_t)c * (D_N * D_N);
        for (int j = 0; j < 8; ++j) {
            const int e = e0 + j;
            float q = 0.f;
            if (kk < 45 && d <= e && e <= 32) {
                float v;
                if (e < 32)      v = Sc[d * D_N + e] * (d == e ? 1.f : 2.f);
                else if (d < 32) v = -2.f * sSm[d];
                else             v = st3;          // d == e == 32
                q = SCALE_F * v;
            }
            _Float16 h = (_Float16)q;
            QF[base + j]       = h;                         // hi
            QF[base + 512 + j] = (_Float16)(q - (float)h);  // lo
        }
    }
}

// ---------------------------------------------------------------------------
// v6 helpers
// ---------------------------------------------------------------------------
__device__ __forceinline__ void gl_lds16(const void* g, void* l) {
    __builtin_amdgcn_global_load_lds(
        (const __attribute__((address_space(1))) unsigned int*)g,
        (__attribute__((address_space(3))) unsigned int*)l, 16, 0, 0);
}

// Stage one 8 KB chunk: 4 waves x 2 issues x (64 lanes x 16 B). LDS dest is
// wave-uniform base (+ lane*16 by HW); global src is per-lane and linear.
__device__ __forceinline__ void stage_chunk(const _Float16* __restrict__ QF,
                                            _Float16* __restrict__ dst,
                                            int chunk, int wid, int lane) {
#pragma unroll
    for (int i = 0; i < 2; ++i) {
        const int slot = i * 4 + wid;
        gl_lds16(QF + (size_t)chunk * CHUNK_F16 + slot * 512 + lane * 8,
                 dst + slot * 512);
    }
}

__device__ __forceinline__ void ldy(const float* sy, int ybase, int hioff,
                                    int kk, float& yd, float (&yw)[8]) {
    int dA, e0;
    mdkk(kk, dA, e0);
    yd = sy[ybase + dA + hioff];
#pragma unroll
    for (int j = 0; j < 8; ++j) yw[j] = sy[ybase + e0 + j];
}

__device__ __forceinline__ void step_compute(const _Float16* __restrict__ buf,
                                             int lane, float yd, const float (&yw)[8],
                                             f32x16 (&acc)[4]) {
    const f16x8* qb = (const f16x8*)buf;     // [ct][hl][lane] 16B frags, literal offs
    f16x8 qh[4], ql[4];
#pragma unroll
    for (int ct = 0; ct < 4; ++ct) {
        qh[ct] = qb[ct * 128 + lane];
        ql[ct] = qb[ct * 128 + 64 + lane];
    }
    // phi build via packed RTZ converts. NOTE: cvt_pkrtz returns a
    // __fp16-based ext-vector; take it via auto and convert element-wise
    // (scalar __fp16 -> _Float16 is a legal implicit conversion).
    f16x8 ph, pl;
#pragma unroll
    for (int j = 0; j < 8; j += 2) {
        float f0 = yd * yw[j], f1 = yd * yw[j + 1];
        auto h2 = __builtin_amdgcn_cvt_pkrtz(f0, f1);
        float r0 = f0 - (float)h2[0];
        float r1 = f1 - (float)h2[1];
        auto l2 = __builtin_amdgcn_cvt_pkrtz(r0, r1);
        ph[j] = h2[0]; ph[j + 1] = h2[1];
        pl[j] = l2[0]; pl[j + 1] = l2[1];
    }
    // same section order as v5 (keep accumulation order == keep numerics)
#pragma unroll
    for (int ct = 0; ct < 4; ++ct)
        acc[ct] = __builtin_amdgcn_mfma_f32_32x32x16_f16(qh[ct], ph, acc[ct], 0, 0, 0);
#pragma unroll
    for (int ct = 0; ct < 4; ++ct)
        acc[ct] = __builtin_amdgcn_mfma_f32_32x32x16_f16(ql[ct], ph, acc[ct], 0, 0, 0);
#pragma unroll
    for (int ct = 0; ct < 4; ++ct)
        acc[ct] = __builtin_amdgcn_mfma_f32_32x32x16_f16(qh[ct], pl, acc[ct], 0, 0, 0);
}

// ---------------------------------------------------------------------------
// Main v6: Q staged block-wide via global_load_lds into a 16 KB LDS double
// buffer (once per block instead of once per wave: L2 traffic 786->193 MB,
// zero Q VGPRs). Per step: {ds_read frags; phi; 12 MFMA; __syncthreads;
// stage chunk t+2 into the buffer just drained}. The barrier's full drain
// makes the stage-early pipeline race-free; stage latency hides under the
// following step's compute. y in LDS (stride 41, conflict-free). Epilogue
// (in-register Gamma -> sum/argmax/class-sums -> direct output) unchanged.
// ---------------------------------------------------------------------------
__global__ __launch_bounds__(256, 2) void k_mainv6(const float* __restrict__ data,
                                                   const _Float16* __restrict__ QF,
                                                   const int* __restrict__ clsp,
                                                   float* __restrict__ out) {
    const int tid  = threadIdx.x;
    const int lane = tid & 63;
    const int wid  = tid >> 6;
    const int b0w  = blockIdx.x * 128 + wid * 32;   // wave's first row
    const int col  = lane & 31;
    const bool hi  = lane >= 32;

    __shared__ float sy[256 * YSTR + 64];
    __shared__ alignas(16) _Float16 qbuf[2][CHUNK_F16];
    __shared__ int lcls[C_N];
    if (tid < C_N) lcls[tid] = clsp[tid];

    const int ybase = tid * YSTR;
    {
        const float4* p0 = (const float4*)(data + (size_t)(b0w + col) * D_N);
#pragma unroll
        for (int i = 0; i < 8; ++i) {
            float4 v = p0[i];
            sy[ybase + 4 * i + 0] = v.x;
            sy[ybase + 4 * i + 1] = v.y;
            sy[ybase + 4 * i + 2] = v.z;
            sy[ybase + 4 * i + 3] = v.w;
        }
        sy[ybase + 32] = 1.f;                        // homogeneous slot
#pragma unroll
        for (int i = 33; i < YSTR; ++i) sy[ybase + i] = 0.f;
        if (tid < 64) sy[256 * YSTR + tid] = 0.f;    // safety pad
    }

    f32x16 acc[4];
#pragma unroll
    for (int ct = 0; ct < 4; ++ct)
#pragma unroll
        for (int g = 0; g < 16; ++g) acc[ct][g] = 0.f;

    // prologue: stage chunks 0,1; barrier drains y stores + stage loads
    stage_chunk(QF, &qbuf[0][0], 0, wid, lane);
    stage_chunk(QF, &qbuf[1][0], 1, wid, lane);
    __syncthreads();

    const int hioff = hi ? 1 : 0;
    float ydA, ywA[8], ydB, ywB[8];
    ldy(sy, ybase, hioff, 0, ydA, ywA);

#pragma clang loop unroll(disable)
    for (int t = 0; t < NKK; t += 2) {
        // ---- step t (buf 0) ----
        ldy(sy, ybase, hioff, t + 1, ydB, ywB);
        step_compute(&qbuf[0][0], lane, ydA, ywA, acc);
        __syncthreads();                              // all waves done with buf0
        if (t + 2 < NKK) stage_chunk(QF, &qbuf[0][0], t + 2, wid, lane);
        // ---- step t+1 (buf 1) ----
        ldy(sy, ybase, hioff, t + 2, ydA, ywA);       // mdkk clamps past end
        step_compute(&qbuf[1][0], lane, ydB, ywB, acc);
        __syncthreads();                              // all waves done with buf1
        if (t + 3 < NKK) stage_chunk(QF, &qbuf[1][0], t + 3, wid, lane);
    }

    // ---------------- fused finalize (Gamma stays in registers) --------------
    // C/D layout (HW-verified): col=lane&31 (b), c = ct*32+(g&3)+8*(g>>2)+4*hi
    const float hoff = hi ? 4.f : 0.f;
    const int* lc = lcls + (hi ? 4 : 0);
    float sum = 0.f, gmax = -1.f, gcf = 0.f;
    float a0 = 0, a1 = 0, a2 = 0, a3 = 0, a4 = 0, a5 = 0, a6 = 0, a7 = 0, a8 = 0, a9 = 0;
#pragma unroll
    for (int ct = 0; ct < 4; ++ct) {
        float psum = 0.f;
#pragma unroll
        for (int g = 0; g < 16; ++g) {
            float v = acc[ct][g];
            float gm;
            asm("v_exp_f32 %0, %1" : "=v"(gm) : "v"(v));   // 2^v = exp(-0.5 d2)
            const int cbase = ct * 32 + (g & 3) + 8 * (g >> 2);
            int cl = lc[cbase];                 // LDS broadcast read
            psum += gm;
            float cf = (float)cbase + hoff;
            if (gm > gmax) { gmax = gm; gcf = cf; }   // lane scans c ascending
            a0 += (cl == 0) ? gm : 0.f;
            a1 += (cl == 1) ? gm : 0.f;
            a2 += (cl == 2) ? gm : 0.f;
            a3 += (cl == 3) ? gm : 0.f;
            a4 += (cl == 4) ? gm : 0.f;
            a5 += (cl == 5) ? gm : 0.f;
            a6 += (cl == 6) ? gm : 0.f;
            a7 += (cl == 7) ? gm : 0.f;
            a8 += (cl == 8) ? gm : 0.f;
            a9 += (cl == 9) ? gm : 0.f;
        }
        sum += psum;
    }

    // combine lane pair (l, l+32): same b-row, complementary c halves
    sum += __shfl_xor(sum, 32, 64);
    {
        float om = __shfl_xor(gmax, 32, 64);
        float oc = __shfl_xor(gcf, 32, 64);
        bool take = (om > gmax) || (om == gmax && oc < gcf);  // first-index tie
        if (take) { gmax = om; gcf = oc; }
    }
    a0 += __shfl_xor(a0, 32, 64);
    a1 += __shfl_xor(a1, 32, 64);
    a2 += __shfl_xor(a2, 32, 64);
    a3 += __shfl_xor(a3, 32, 64);
    a4 += __shfl_xor(a4, 32, 64);
    a5 += __shfl_xor(a5, 32, 64);
    a6 += __shfl_xor(a6, 32, 64);
    a7 += __shfl_xor(a7, 32, 64);
    a8 += __shfl_xor(a8, 32, 64);
    a9 += __shfl_xor(a9, 32, 64);

    if (!hi) {
        const int b = b0w + col;
        float inv = 1.0f / (sum + EPS_F);
        float ls[K_N] = {a0 * inv, a1 * inv, a2 * inv, a3 * inv, a4 * inv,
                         a5 * inv, a6 * inv, a7 * inv, a8 * inv, a9 * inv};
        float best = -1.f;
        int bk = 0;
#pragma unroll
        for (int k = 0; k < K_N; ++k)
            if (ls[k] > best) { best = ls[k]; bk = k; }
        float2* o2 = (float2*)(out + (size_t)b * K_N);   // b*40B is 8B-aligned
#pragma unroll
        for (int k2 = 0; k2 < K_N / 2; ++k2)
            o2[k2] = make_float2(ls[2 * k2], ls[2 * k2 + 1]);
        out[(size_t)B_N * K_N + b] = (float)bk;
        out[(size_t)B_N * K_N + B_N + b] = gcf;
    }
}

// ---------------------------------------------------------------------------
extern "C" void kernel_launch(void* const* d_in, const int* in_sizes, int n_in,
                              void* d_out, int out_size, void* d_ws, size_t ws_size,
                              hipStream_t stream) {
    const float* data   = (const float*)d_in[0];   // [B, D]
    const float* mu     = (const float*)d_in[1];   // [C, D]
    const float* S      = (const float*)d_in[2];   // [C, D, D]
    const int*   onehot = (const int*)d_in[3];     // [C, K]
    float* out = (float*)d_out;

    // ws: QF [QF_N f16] | cls [C]
    _Float16* QF  = (_Float16*)d_ws;
    int*      cls = (int*)(QF + QF_N);

    hipLaunchKernelGGL(k_prep, dim3(C_N), dim3(128), 0, stream,
                       S, mu, onehot, QF, cls);
    hipLaunchKernelGGL(k_mainv6, dim3(B_N / 128), dim3(256), 0, stream,
                       data, QF, cls, out);
}